// Round 1
// baseline (176.711 us; speedup 1.0000x reference)
//
#include <hip/hip_runtime.h>
#include <math.h>

#define N_FRAMES 4
#define N_FACES  320
#define N_VERTS  162
#define IMG_H    128
#define IMG_W    128
#define FD_STRIDE 12   // ax,ay,bx,by,cx,cy,z0,z1,z2,invden,valid,pad

// ---------- small math helpers (fp32, op-order matched to the JAX reference) ----------

__device__ __forceinline__ void q_to_aa(const float* q, float* aa) {
    float q1 = q[1], q2 = q[2], q3 = q[3];
    float sin_sq = (q1 * q1 + q2 * q2) + q3 * q3;
    float sin_t = sqrtf(sin_sq + 1e-20f);
    float cos_t = q[0];
    float two_theta = (cos_t < 0.0f) ? (2.0f * atan2f(-sin_t, -cos_t))
                                     : (2.0f * atan2f(sin_t, cos_t));
    float k = (sin_sq > 1e-12f) ? (two_theta / sin_t) : 2.0f;
    aa[0] = q1 * k; aa[1] = q2 * k; aa[2] = q3 * k;
}

__device__ __forceinline__ void aa_to_R(const float* aa, float* R) {
    float th = sqrtf(((aa[0] * aa[0] + aa[1] * aa[1]) + aa[2] * aa[2]) + 1e-12f);
    float kx = aa[0] / th, ky = aa[1] / th, kz = aa[2] / th;
    float K[9] = { 0.0f, -kz,  ky,
                   kz,  0.0f, -kx,
                  -ky,   kx, 0.0f };
    float s = sinf(th), c = cosf(th);
    float KK[9];
    for (int i = 0; i < 3; ++i)
        for (int j = 0; j < 3; ++j)
            KK[i*3+j] = (K[i*3+0] * K[0*3+j] + K[i*3+1] * K[1*3+j]) + K[i*3+2] * K[2*3+j];
    float omc = 1.0f - c;
    for (int i = 0; i < 9; ++i) {
        float eye = (i == 0 || i == 4 || i == 8) ? 1.0f : 0.0f;
        R[i] = (eye + s * K[i]) + omc * KK[i];
    }
}

__device__ __forceinline__ void mat3mul(const float* A, const float* B, float* C) {
    for (int i = 0; i < 3; ++i)
        for (int j = 0; j < 3; ++j)
            C[i*3+j] = (A[i*3+0] * B[0*3+j] + A[i*3+1] * B[1*3+j]) + A[i*3+2] * B[2*3+j];
}

// ---------- kernel 1: rotation chain, vertex transform, per-face setup ----------

__global__ void __launch_bounds__(256)
setup_kernel(const float* __restrict__ verts_in,   // 162*3
             const float* __restrict__ transl,     // (1,1,1,2,3) -> 6 floats
             const float* __restrict__ quat,       // (1,1,2,4)   -> 8 floats
             const float* __restrict__ expv,       // 1 float
             const int*   __restrict__ faces,      // 320*3
             float* __restrict__ faceData)         // 4*320*FD_STRIDE
{
    __shared__ float rots[N_FRAMES][9];
    __shared__ float sv[N_FRAMES][N_VERTS * 3];    // camera-space verts
    int tid = threadIdx.x;

    if (tid == 0) {
        float aa0[3], aa1[3], R0[9], step[9];
        q_to_aa(quat, aa0);
        aa_to_R(aa0, R0);
        q_to_aa(quat + 4, aa1);                    // angles (ROT_DIVIDE = 1)
        float e = expv[0];
        float arg[3];
        for (int i = 0; i < 3; ++i) arg[i] = (e * aa1[i]) / 4.0f;   // exp*angles/FMO_STEPS
        aa_to_R(arg, step);
        float cur[9];
        for (int i = 0; i < 9; ++i) { cur[i] = R0[i]; rots[0][i] = R0[i]; }
        for (int k = 1; k < N_FRAMES; ++k) {
            float nxt[9];
            mat3mul(cur, step, nxt);               // rot = rot @ rot_step (sequential)
            for (int i = 0; i < 9; ++i) { cur[i] = nxt[i]; rots[k][i] = nxt[i]; }
        }
    }
    __syncthreads();

    float e = expv[0];
    float t0 = transl[0], t1 = transl[1], t2 = transl[2];   // trans_start
    float u0 = transl[3], u1 = transl[4], u2 = transl[5];   // translation term p=1

    for (int item = tid; item < N_FRAMES * N_VERTS; item += blockDim.x) {
        int k = item / N_VERTS, v = item - k * N_VERTS;
        float te = (float)((double)k / 3.0) * e;            // f32(linspace ti) * exp
        float vx = verts_in[v*3+0], vy = verts_in[v*3+1], vz = verts_in[v*3+2];
        const float* R = rots[k];
        float dx_ = (R[0] * vx + R[1] * vy) + R[2] * vz;
        float dy_ = (R[3] * vx + R[4] * vy) + R[5] * vz;
        float dz_ = (R[6] * vx + R[7] * vy) + R[8] * vz;
        float x = (dx_ + t0) + te * u0;
        float y = (dy_ + t1) + te * u1;
        float z = (dz_ + t2) + te * u2;
        z = z - 2.0f;                                       // v_cam = verts - [0,0,CAM_DIST]
        sv[k][v*3+0] = x; sv[k][v*3+1] = y; sv[k][v*3+2] = z;
    }
    __syncthreads();

    const float FOCAL = (float)(1.0 / tan(1.57 / 4.0));

    for (int item = tid; item < N_FRAMES * N_FACES; item += blockDim.x) {
        int k = item / N_FACES, f = item - k * N_FACES;
        int i0 = faces[f*3+0], i1 = faces[f*3+1], i2 = faces[f*3+2];
        const float* A = &sv[k][i0*3];
        const float* B = &sv[k][i1*3];
        const float* C = &sv[k][i2*3];
        // face-normal z (normalization preserves sign; only fn_z > 0 matters)
        float ux = B[0] - A[0], uy = B[1] - A[1];
        float wx = C[0] - A[0], wy = C[1] - A[1];
        float nz = ux * wy - uy * wx;
        // projection: img = (FOCAL * xy) / (-z + 1e-10)
        float da = -A[2] + 1e-10f, db = -B[2] + 1e-10f, dc = -C[2] + 1e-10f;
        float ax = (FOCAL * A[0]) / da, ay = (FOCAL * A[1]) / da;
        float bx = (FOCAL * B[0]) / db, by = (FOCAL * B[1]) / db;
        float cx = (FOCAL * C[0]) / dc, cy = (FOCAL * C[1]) / dc;
        float e0x = bx - ax, e0y = by - ay;
        float e1x = cx - ax, e1y = cy - ay;
        float den = e0x * e1y - e0y * e1x;
        int dok = fabsf(den) > 1e-10f;
        float invden = dok ? (1.0f / den) : 0.0f;
        float valid = (dok && (nz > 0.0f)) ? 1.0f : 0.0f;
        float* fd = faceData + (k * N_FACES + f) * FD_STRIDE;
        fd[0] = ax; fd[1] = ay; fd[2] = bx; fd[3] = by; fd[4] = cx; fd[5] = cy;
        fd[6] = A[2]; fd[7] = B[2]; fd[8] = C[2];
        fd[9] = invden; fd[10] = valid; fd[11] = 0.0f;
    }
}

// ---------- kernel 2: per-pixel rasterization + texture sample ----------

__global__ void __launch_bounds__(256)
raster_kernel(const float* __restrict__ faceData,
              const float* __restrict__ ffeat,    // (320,3,2)
              const float* __restrict__ tex,      // (3,256,256)
              float* __restrict__ out,            // (4,4,128,128)
              float* __restrict__ maskbuf)        // (4,128,128)
{
    int frame = blockIdx.x >> 6;
    int pix = (blockIdx.x & 63) * 256 + threadIdx.x;   // 0..16383
    int i = pix >> 7, j = pix & 127;

    __shared__ float fd[N_FACES * FD_STRIDE];
    for (int t = threadIdx.x; t < N_FACES * FD_STRIDE; t += 256)
        fd[t] = faceData[frame * N_FACES * FD_STRIDE + t];
    __syncthreads();

    float px = (float)(-1.0 + 2.0 * (double)j / 127.0);   // xs = linspace(-1,1,128)
    float py = (float)( 1.0 - 2.0 * (double)i / 127.0);   // ys = linspace(1,-1,128)

    float best = -1e10f;
    int bestf = 0;
    float bw0 = 0.0f, bw1 = 0.0f, bw2 = 0.0f;
    bool hit = false;
    float P = 1.0f;

    for (int f = 0; f < N_FACES; ++f) {
        const float* d = &fd[f * FD_STRIDE];
        float ax = d[0], ay = d[1], bx = d[2], by = d[3], cx = d[4], cy = d[5];
        float z0 = d[6], z1 = d[7], z2 = d[8], invden = d[9];
        bool valid = d[10] != 0.0f;

        float e0x = bx - ax, e0y = by - ay;
        float e1x = cx - ax, e1y = cy - ay;
        float dx = px - ax, dy = py - ay;
        float w1 = (dx * e1y - dy * e1x) * invden;
        float w2 = (e0x * dy - e0y * dx) * invden;
        float w0 = (1.0f - w1) - w2;
        bool inside = (w0 >= 0.0f) & (w1 >= 0.0f) & (w2 >= 0.0f) & valid;
        float zi = (w0 * z0 + w1 * z1) + w2 * z2;
        float score = inside ? zi : -1e10f;
        if (score > best) { best = score; bestf = f; bw0 = w0; bw1 = w1; bw2 = w2; }
        hit = hit | inside;

        // edge 0: a -> b
        float dd;
        {
            float ex = e0x, ey = e0y, rx = dx, ry = dy;
            float L2 = (ex * ex + ey * ey) + 1e-12f;
            float t = fminf(fmaxf((rx * ex + ry * ey) / L2, 0.0f), 1.0f);
            float dxe = rx - t * ex, dye = ry - t * ey;
            dd = dxe * dxe + dye * dye;
        }
        // edge 1: b -> c
        {
            float ex = cx - bx, ey = cy - by, rx = px - bx, ry = py - by;
            float L2 = (ex * ex + ey * ey) + 1e-12f;
            float t = fminf(fmaxf((rx * ex + ry * ey) / L2, 0.0f), 1.0f);
            float dxe = rx - t * ex, dye = ry - t * ey;
            float d1 = dxe * dxe + dye * dye;
            dd = fminf(dd, d1);
        }
        // edge 2: c -> a
        {
            float ex = ax - cx, ey = ay - cy, rx = px - cx, ry = py - cy;
            float L2 = (ex * ex + ey * ey) + 1e-12f;
            float t = fminf(fmaxf((rx * ex + ry * ey) / L2, 0.0f), 1.0f);
            float dxe = rx - t * ex, dye = ry - t * ey;
            float d1 = dxe * dxe + dye * dye;
            dd = fminf(dd, d1);
        }
        float d2 = inside ? 0.0f : dd;
        float prob = valid ? expf(-7000.0f * d2) : 0.0f;
        P *= (1.0f - prob);
    }

    float mask = 1.0f - P;

    float uv0 = 0.0f, uv1 = 0.0f;
    if (hit) {
        const float* fp = ffeat + bestf * 6;   // (3 verts, 2 channels)
        uv0 = (fp[0] * bw0 + fp[2] * bw1) + fp[4] * bw2;
        uv1 = (fp[1] * bw0 + fp[3] * bw1) + fp[5] * bw2;
    }
    // texture_sample (also runs at uv=(0,0) for non-hit pixels, matching ref)
    float u = fminf(fmaxf(uv0, 0.0f), 1.0f) * 255.0f;
    float v = (1.0f - fminf(fmaxf(uv1, 0.0f), 1.0f)) * 255.0f;
    float x0f = floorf(u), y0f = floorf(v);
    float fx = u - x0f, fy = v - y0f;
    int x0i = min(max((int)x0f, 0), 255);
    int x1i = min(x0i + 1, 255);
    int y0i = min(max((int)y0f, 0), 255);
    int y1i = min(y0i + 1, 255);

    for (int c = 0; c < 3; ++c) {
        const float* tc = tex + c * 65536;
        float t00 = tc[y0i * 256 + x0i];
        float t01 = tc[y0i * 256 + x1i];
        float t10 = tc[y1i * 256 + x0i];
        float t11 = tc[y1i * 256 + x1i];
        float val = (t00 * (1.0f - fx)) * (1.0f - fy);
        val = val + (t01 * fx) * (1.0f - fy);
        val = val + (t10 * (1.0f - fx)) * fy;
        val = val + (t11 * fx) * fy;
        out[((frame * 4 + c) * IMG_H + i) * IMG_W + j] = val;
    }
    maskbuf[(frame * IMG_H + i) * IMG_W + j] = mask;
}

// ---------- kernel 3: 5x5 erode (window min, SAME padding ignored) ----------

__global__ void __launch_bounds__(256)
erode_kernel(const float* __restrict__ maskbuf, float* __restrict__ out)
{
    int frame = blockIdx.x >> 6;
    int pix = (blockIdx.x & 63) * 256 + threadIdx.x;
    int i = pix >> 7, j = pix & 127;
    float m = 1e30f;
    for (int di = -2; di <= 2; ++di) {
        int ii = i + di;
        if (ii < 0 || ii >= IMG_H) continue;
        for (int dj = -2; dj <= 2; ++dj) {
            int jj = j + dj;
            if (jj < 0 || jj >= IMG_W) continue;
            m = fminf(m, maskbuf[(frame * IMG_H + ii) * IMG_W + jj]);
        }
    }
    out[((frame * 4 + 3) * IMG_H + i) * IMG_W + j] = m;
}

// ---------- launcher ----------

extern "C" void kernel_launch(void* const* d_in, const int* in_sizes, int n_in,
                              void* d_out, int out_size, void* d_ws, size_t ws_size,
                              hipStream_t stream) {
    const float* vertices      = (const float*)d_in[0];
    const float* translation   = (const float*)d_in[1];
    const float* quaternion    = (const float*)d_in[2];
    const float* expv          = (const float*)d_in[3];
    const float* face_features = (const float*)d_in[4];
    const float* texture_maps  = (const float*)d_in[5];
    const int*   faces         = (const int*)d_in[6];
    float* out = (float*)d_out;

    float* faceData = (float*)d_ws;                              // 4*320*12 floats
    float* maskbuf  = faceData + N_FRAMES * N_FACES * FD_STRIDE; // 4*128*128 floats

    setup_kernel<<<1, 256, 0, stream>>>(vertices, translation, quaternion, expv,
                                        faces, faceData);
    raster_kernel<<<N_FRAMES * 64, 256, 0, stream>>>(faceData, face_features,
                                                     texture_maps, out, maskbuf);
    erode_kernel<<<N_FRAMES * 64, 256, 0, stream>>>(maskbuf, out);
}

// Round 2
// 114.029 us; speedup vs baseline: 1.5497x; 1.5497x over previous
//
#include <hip/hip_runtime.h>
#include <math.h>

#define N_FRAMES 4
#define N_FACES  320
#define N_VERTS  162
#define IMG_H    128
#define IMG_W    128
#define FD_STRIDE 24      // 6 float4s per face (see layout below)
#define CHUNKS   4        // lanes per pixel (face-split factor)
#define FPC      (N_FACES / CHUNKS)   // 80 faces per chunk

// Per-face data layout (float4 groups):
//  q0: ax, ay, e0x, e0y          (a vertex, edge a->b)
//  q1: e1x, e1y, invden, valid   (edge a->c, 1/denom, validity flag)
//  q2: z0, z1, z2, invL2_0       (vertex depths, 1/L2 of edge 0)
//  q3: bx, by, e12x, e12y        (b vertex, edge b->c)
//  q4: cx, cy, e20x, e20y        (c vertex, edge c->a)
//  q5: invL2_1, invL2_2, 0, 0

// ---------- small math helpers (fp32, op-order matched to the JAX reference) ----------

__device__ __forceinline__ void q_to_aa(const float* q, float* aa) {
    float q1 = q[1], q2 = q[2], q3 = q[3];
    float sin_sq = (q1 * q1 + q2 * q2) + q3 * q3;
    float sin_t = sqrtf(sin_sq + 1e-20f);
    float cos_t = q[0];
    float two_theta = (cos_t < 0.0f) ? (2.0f * atan2f(-sin_t, -cos_t))
                                     : (2.0f * atan2f(sin_t, cos_t));
    float k = (sin_sq > 1e-12f) ? (two_theta / sin_t) : 2.0f;
    aa[0] = q1 * k; aa[1] = q2 * k; aa[2] = q3 * k;
}

__device__ __forceinline__ void aa_to_R(const float* aa, float* R) {
    float th = sqrtf(((aa[0] * aa[0] + aa[1] * aa[1]) + aa[2] * aa[2]) + 1e-12f);
    float kx = aa[0] / th, ky = aa[1] / th, kz = aa[2] / th;
    float K[9] = { 0.0f, -kz,  ky,
                   kz,  0.0f, -kx,
                  -ky,   kx, 0.0f };
    float s = sinf(th), c = cosf(th);
    float KK[9];
    for (int i = 0; i < 3; ++i)
        for (int j = 0; j < 3; ++j)
            KK[i*3+j] = (K[i*3+0] * K[0*3+j] + K[i*3+1] * K[1*3+j]) + K[i*3+2] * K[2*3+j];
    float omc = 1.0f - c;
    for (int i = 0; i < 9; ++i) {
        float eye = (i == 0 || i == 4 || i == 8) ? 1.0f : 0.0f;
        R[i] = (eye + s * K[i]) + omc * KK[i];
    }
}

__device__ __forceinline__ void mat3mul(const float* A, const float* B, float* C) {
    for (int i = 0; i < 3; ++i)
        for (int j = 0; j < 3; ++j)
            C[i*3+j] = (A[i*3+0] * B[0*3+j] + A[i*3+1] * B[1*3+j]) + A[i*3+2] * B[2*3+j];
}

// ---------- kernel 1: rotation chain, vertex transform, per-face setup ----------

__global__ void __launch_bounds__(256)
setup_kernel(const float* __restrict__ verts_in,   // 162*3
             const float* __restrict__ transl,     // 6 floats
             const float* __restrict__ quat,       // 8 floats
             const float* __restrict__ expv,       // 1 float
             const int*   __restrict__ faces,      // 320*3
             float* __restrict__ faceData)         // 4*320*FD_STRIDE
{
    __shared__ float rots[N_FRAMES][9];
    __shared__ float sv[N_FRAMES][N_VERTS * 3];    // camera-space verts
    int tid = threadIdx.x;

    if (tid == 0) {
        float aa0[3], aa1[3], R0[9], step[9];
        q_to_aa(quat, aa0);
        aa_to_R(aa0, R0);
        q_to_aa(quat + 4, aa1);                    // angles (ROT_DIVIDE = 1)
        float e = expv[0];
        float arg[3];
        for (int i = 0; i < 3; ++i) arg[i] = (e * aa1[i]) / 4.0f;   // exp*angles/FMO_STEPS
        aa_to_R(arg, step);
        float cur[9];
        for (int i = 0; i < 9; ++i) { cur[i] = R0[i]; rots[0][i] = R0[i]; }
        for (int k = 1; k < N_FRAMES; ++k) {
            float nxt[9];
            mat3mul(cur, step, nxt);               // rot = rot @ rot_step (sequential)
            for (int i = 0; i < 9; ++i) { cur[i] = nxt[i]; rots[k][i] = nxt[i]; }
        }
    }
    __syncthreads();

    float e = expv[0];
    float t0 = transl[0], t1 = transl[1], t2 = transl[2];   // trans_start
    float u0 = transl[3], u1 = transl[4], u2 = transl[5];   // translation term p=1

    for (int item = tid; item < N_FRAMES * N_VERTS; item += blockDim.x) {
        int k = item / N_VERTS, v = item - k * N_VERTS;
        float te = (float)((double)k / 3.0) * e;            // f32(linspace ti) * exp
        float vx = verts_in[v*3+0], vy = verts_in[v*3+1], vz = verts_in[v*3+2];
        const float* R = rots[k];
        float dx_ = (R[0] * vx + R[1] * vy) + R[2] * vz;
        float dy_ = (R[3] * vx + R[4] * vy) + R[5] * vz;
        float dz_ = (R[6] * vx + R[7] * vy) + R[8] * vz;
        float x = (dx_ + t0) + te * u0;
        float y = (dy_ + t1) + te * u1;
        float z = (dz_ + t2) + te * u2;
        z = z - 2.0f;                                       // v_cam = verts - [0,0,CAM_DIST]
        sv[k][v*3+0] = x; sv[k][v*3+1] = y; sv[k][v*3+2] = z;
    }
    __syncthreads();

    const float FOCAL = (float)(1.0 / tan(1.57 / 4.0));

    for (int item = tid; item < N_FRAMES * N_FACES; item += blockDim.x) {
        int k = item / N_FACES, f = item - k * N_FACES;
        int i0 = faces[f*3+0], i1 = faces[f*3+1], i2 = faces[f*3+2];
        const float* A = &sv[k][i0*3];
        const float* B = &sv[k][i1*3];
        const float* C = &sv[k][i2*3];
        float ux = B[0] - A[0], uy = B[1] - A[1];
        float wx = C[0] - A[0], wy = C[1] - A[1];
        float nz = ux * wy - uy * wx;                       // sign of face-normal z
        float da = -A[2] + 1e-10f, db = -B[2] + 1e-10f, dc = -C[2] + 1e-10f;
        float ax = (FOCAL * A[0]) / da, ay = (FOCAL * A[1]) / da;
        float bx = (FOCAL * B[0]) / db, by = (FOCAL * B[1]) / db;
        float cx = (FOCAL * C[0]) / dc, cy = (FOCAL * C[1]) / dc;
        float e0x = bx - ax, e0y = by - ay;                 // a->b
        float e1x = cx - ax, e1y = cy - ay;                 // a->c
        float e12x = cx - bx, e12y = cy - by;               // b->c
        float e20x = ax - cx, e20y = ay - cy;               // c->a
        float den = e0x * e1y - e0y * e1x;
        int dok = fabsf(den) > 1e-10f;
        float invden = dok ? (1.0f / den) : 0.0f;
        float valid = (dok && (nz > 0.0f)) ? 1.0f : 0.0f;
        float L2_0 = (e0x * e0x + e0y * e0y) + 1e-12f;
        float L2_1 = (e12x * e12x + e12y * e12y) + 1e-12f;
        float L2_2 = (e20x * e20x + e20y * e20y) + 1e-12f;
        float* fd = faceData + (k * N_FACES + f) * FD_STRIDE;
        fd[0]  = ax;   fd[1]  = ay;   fd[2]  = e0x;  fd[3]  = e0y;
        fd[4]  = e1x;  fd[5]  = e1y;  fd[6]  = invden; fd[7] = valid;
        fd[8]  = A[2]; fd[9]  = B[2]; fd[10] = C[2]; fd[11] = 1.0f / L2_0;
        fd[12] = bx;   fd[13] = by;   fd[14] = e12x; fd[15] = e12y;
        fd[16] = cx;   fd[17] = cy;   fd[18] = e20x; fd[19] = e20y;
        fd[20] = 1.0f / L2_1; fd[21] = 1.0f / L2_2; fd[22] = 0.0f; fd[23] = 0.0f;
    }
}

// ---------- kernel 2: per-pixel rasterization + texture sample ----------
// 4 lanes per pixel, each handling 80 faces; butterfly combine over the quad.

__global__ void __launch_bounds__(256)
raster_kernel(const float* __restrict__ faceData,
              const float* __restrict__ ffeat,    // (320,3,2)
              const float* __restrict__ tex,      // (3,256,256)
              float* __restrict__ out,            // (4,4,128,128)
              float* __restrict__ maskbuf)        // (4,128,128)
{
    int frame = blockIdx.x >> 8;                   // 1024 blocks: 256 per frame
    int blk   = blockIdx.x & 255;
    int tid   = threadIdx.x;
    int chunk = tid & 3;                           // face chunk for this lane
    int pix   = blk * 64 + (tid >> 2);             // 64 pixels per block
    int i = pix >> 7, j = pix & 127;

    // LDS: interleaved so quad lanes (chunk 0..3) hit distinct banks.
    // float4 index for (face fi of chunk c, group q) = (fi*4 + c)*6 + q
    __shared__ float4 fd4[N_FACES * 6];
    const float4* g = (const float4*)(faceData + frame * N_FACES * FD_STRIDE);
    for (int idx = tid; idx < N_FACES * 6; idx += 256) {
        int f = idx / 6, q = idx - f * 6;
        int c = f / FPC, fi = f - c * FPC;
        fd4[(fi * 4 + c) * 6 + q] = g[idx];
    }
    __syncthreads();

    float px = (float)(-1.0 + 2.0 * (double)j / 127.0);   // xs = linspace(-1,1,128)
    float py = (float)( 1.0 - 2.0 * (double)i / 127.0);   // ys = linspace(1,-1,128)

    float best = -1e10f;
    int bestf = 0;
    float bw0 = 0.0f, bw1 = 0.0f, bw2 = 0.0f;
    float P = 1.0f;

    const float4* fb = &fd4[chunk * 6];
    for (int fi = 0; fi < FPC; ++fi) {
        const float4* d = fb + fi * (4 * 6);
        float4 q0 = d[0], q1 = d[1], q2 = d[2], q3 = d[3], q4 = d[4], q5 = d[5];

        float dx = px - q0.x, dy = py - q0.y;
        float w1 = (dx * q1.y - dy * q1.x) * q1.z;         // (dx*e1y - dy*e1x)*invden
        float w2 = (q0.z * dy - q0.w * dx) * q1.z;         // (e0x*dy - e0y*dx)*invden
        float w0 = (1.0f - w1) - w2;
        bool valid = q1.w != 0.0f;
        bool inside = (w0 >= 0.0f) & (w1 >= 0.0f) & (w2 >= 0.0f) & valid;
        float zi = (w0 * q2.x + w1 * q2.y) + w2 * q2.z;
        float score = inside ? zi : -1e10f;
        if (score > best) { best = score; bestf = chunk * FPC + fi; bw0 = w0; bw1 = w1; bw2 = w2; }

        // edge 0: a->b  (rx,ry = dx,dy; ex,ey = e0; invL2 in q2.w)
        float t0 = fminf(fmaxf((dx * q0.z + dy * q0.w) * q2.w, 0.0f), 1.0f);
        float x0 = dx - t0 * q0.z, y0 = dy - t0 * q0.w;
        float dd = x0 * x0 + y0 * y0;
        // edge 1: b->c
        float rx1 = px - q3.x, ry1 = py - q3.y;
        float t1 = fminf(fmaxf((rx1 * q3.z + ry1 * q3.w) * q5.x, 0.0f), 1.0f);
        float x1 = rx1 - t1 * q3.z, y1 = ry1 - t1 * q3.w;
        dd = fminf(dd, x1 * x1 + y1 * y1);
        // edge 2: c->a
        float rx2 = px - q4.x, ry2 = py - q4.y;
        float t2 = fminf(fmaxf((rx2 * q4.z + ry2 * q4.w) * q5.y, 0.0f), 1.0f);
        float x2 = rx2 - t2 * q4.z, y2 = ry2 - t2 * q4.w;
        dd = fminf(dd, x2 * x2 + y2 * y2);

        float d2 = inside ? 0.0f : dd;
        float prob = valid ? __expf(-7000.0f * d2) : 0.0f;
        P *= (1.0f - prob);
    }

    // butterfly combine across the quad (lanes chunk 0..3 of the same pixel)
    for (int m = 1; m <= 2; m <<= 1) {
        float oS  = __shfl_xor(best, m);
        int   oF  = __shfl_xor(bestf, m);
        float o0  = __shfl_xor(bw0, m);
        float o1  = __shfl_xor(bw1, m);
        float o2  = __shfl_xor(bw2, m);
        bool take = (oS > best) || ((oS == best) && (oF < bestf));  // argmax = first max
        if (take) { best = oS; bestf = oF; bw0 = o0; bw1 = o1; bw2 = o2; }
        P *= __shfl_xor(P, m);
    }

    if (chunk == 0) {
        bool hit = best != -1e10f;
        float uv0 = 0.0f, uv1 = 0.0f;
        if (hit) {
            const float* fp = ffeat + bestf * 6;
            uv0 = (fp[0] * bw0 + fp[2] * bw1) + fp[4] * bw2;
            uv1 = (fp[1] * bw0 + fp[3] * bw1) + fp[5] * bw2;
        }
        float u = fminf(fmaxf(uv0, 0.0f), 1.0f) * 255.0f;
        float v = (1.0f - fminf(fmaxf(uv1, 0.0f), 1.0f)) * 255.0f;
        float x0f = floorf(u), y0f = floorf(v);
        float fx = u - x0f, fy = v - y0f;
        int x0i = min(max((int)x0f, 0), 255);
        int x1i = min(x0i + 1, 255);
        int y0i = min(max((int)y0f, 0), 255);
        int y1i = min(y0i + 1, 255);

        for (int c = 0; c < 3; ++c) {
            const float* tc = tex + c * 65536;
            float t00 = tc[y0i * 256 + x0i];
            float t01 = tc[y0i * 256 + x1i];
            float t10 = tc[y1i * 256 + x0i];
            float t11 = tc[y1i * 256 + x1i];
            float val = (t00 * (1.0f - fx)) * (1.0f - fy);
            val = val + (t01 * fx) * (1.0f - fy);
            val = val + (t10 * (1.0f - fx)) * fy;
            val = val + (t11 * fx) * fy;
            out[((frame * 4 + c) * IMG_H + i) * IMG_W + j] = val;
        }
        maskbuf[(frame * IMG_H + i) * IMG_W + j] = 1.0f - P;
    }
}

// ---------- kernel 3: 5x5 erode (window min over valid region) ----------

__global__ void __launch_bounds__(256)
erode_kernel(const float* __restrict__ maskbuf, float* __restrict__ out)
{
    int frame = blockIdx.x >> 6;
    int pix = (blockIdx.x & 63) * 256 + threadIdx.x;
    int i = pix >> 7, j = pix & 127;
    float m = 1e30f;
    for (int di = -2; di <= 2; ++di) {
        int ii = i + di;
        if (ii < 0 || ii >= IMG_H) continue;
        for (int dj = -2; dj <= 2; ++dj) {
            int jj = j + dj;
            if (jj < 0 || jj >= IMG_W) continue;
            m = fminf(m, maskbuf[(frame * IMG_H + ii) * IMG_W + jj]);
        }
    }
    out[((frame * 4 + 3) * IMG_H + i) * IMG_W + j] = m;
}

// ---------- launcher ----------

extern "C" void kernel_launch(void* const* d_in, const int* in_sizes, int n_in,
                              void* d_out, int out_size, void* d_ws, size_t ws_size,
                              hipStream_t stream) {
    const float* vertices      = (const float*)d_in[0];
    const float* translation   = (const float*)d_in[1];
    const float* quaternion    = (const float*)d_in[2];
    const float* expv          = (const float*)d_in[3];
    const float* face_features = (const float*)d_in[4];
    const float* texture_maps  = (const float*)d_in[5];
    const int*   faces         = (const int*)d_in[6];
    float* out = (float*)d_out;

    float* faceData = (float*)d_ws;                              // 4*320*24 floats
    float* maskbuf  = faceData + N_FRAMES * N_FACES * FD_STRIDE; // 4*128*128 floats

    setup_kernel<<<1, 256, 0, stream>>>(vertices, translation, quaternion, expv,
                                        faces, faceData);
    raster_kernel<<<N_FRAMES * 256, 256, 0, stream>>>(faceData, face_features,
                                                      texture_maps, out, maskbuf);
    erode_kernel<<<N_FRAMES * 64, 256, 0, stream>>>(maskbuf, out);
}

// Round 3
// 96.026 us; speedup vs baseline: 1.8403x; 1.1875x over previous
//
#include <hip/hip_runtime.h>
#include <math.h>

#define N_FRAMES 4
#define N_FACES  320
#define N_VERTS  162
#define IMG_H    128
#define IMG_W    128
#define FD_STRIDE 20      // 5 float4s per compacted face
#define CHUNKS   8        // lanes per pixel (face-split factor)

// Compacted per-face record (5 float4s):
//  q0: ax, ay, e0x, e0y            (a vertex, edge a->b)
//  q1: e1x, e1y, invden, origidx   (edge a->c, 1/denom, original face index)
//  q2: z0, z1, z2, invL2_0
//  q3: bx, by, e12x, e12y          (b vertex, edge b->c)
//  q4: cx, cy, invL2_1, invL2_2    (edge c->a = -e1 exactly)

// ---------- small math helpers (fp32, op-order matched to the JAX reference) ----------

__device__ __forceinline__ void q_to_aa(const float* q, float* aa) {
    float q1 = q[1], q2 = q[2], q3 = q[3];
    float sin_sq = (q1 * q1 + q2 * q2) + q3 * q3;
    float sin_t = sqrtf(sin_sq + 1e-20f);
    float cos_t = q[0];
    float two_theta = (cos_t < 0.0f) ? (2.0f * atan2f(-sin_t, -cos_t))
                                     : (2.0f * atan2f(sin_t, cos_t));
    float k = (sin_sq > 1e-12f) ? (two_theta / sin_t) : 2.0f;
    aa[0] = q1 * k; aa[1] = q2 * k; aa[2] = q3 * k;
}

__device__ __forceinline__ void aa_to_R(const float* aa, float* R) {
    float th = sqrtf(((aa[0] * aa[0] + aa[1] * aa[1]) + aa[2] * aa[2]) + 1e-12f);
    float kx = aa[0] / th, ky = aa[1] / th, kz = aa[2] / th;
    float K[9] = { 0.0f, -kz,  ky,
                   kz,  0.0f, -kx,
                  -ky,   kx, 0.0f };
    float s = sinf(th), c = cosf(th);
    float KK[9];
    for (int i = 0; i < 3; ++i)
        for (int j = 0; j < 3; ++j)
            KK[i*3+j] = (K[i*3+0] * K[0*3+j] + K[i*3+1] * K[1*3+j]) + K[i*3+2] * K[2*3+j];
    float omc = 1.0f - c;
    for (int i = 0; i < 9; ++i) {
        float eye = (i == 0 || i == 4 || i == 8) ? 1.0f : 0.0f;
        R[i] = (eye + s * K[i]) + omc * KK[i];
    }
}

__device__ __forceinline__ void mat3mul(const float* A, const float* B, float* C) {
    for (int i = 0; i < 3; ++i)
        for (int j = 0; j < 3; ++j)
            C[i*3+j] = (A[i*3+0] * B[0*3+j] + A[i*3+1] * B[1*3+j]) + A[i*3+2] * B[2*3+j];
}

// ---------- kernel 1: rotation chain, vertex transform, face setup + compaction ----------

__global__ void __launch_bounds__(256)
setup_kernel(const float* __restrict__ verts_in,   // 162*3
             const float* __restrict__ transl,     // 6 floats
             const float* __restrict__ quat,       // 8 floats
             const float* __restrict__ expv,       // 1 float
             const int*   __restrict__ faces,      // 320*3
             int*   __restrict__ faceCount,        // 4 ints
             float* __restrict__ faceData)         // 4*320*FD_STRIDE
{
    __shared__ float rots[N_FRAMES][9];
    __shared__ float sv[N_FRAMES][N_VERTS * 3];    // camera-space verts
    int tid = threadIdx.x;

    if (tid == 0) {
        float aa0[3], aa1[3], R0[9], step[9];
        q_to_aa(quat, aa0);
        aa_to_R(aa0, R0);
        q_to_aa(quat + 4, aa1);                    // angles (ROT_DIVIDE = 1)
        float e = expv[0];
        float arg[3];
        for (int i = 0; i < 3; ++i) arg[i] = (e * aa1[i]) / 4.0f;   // exp*angles/FMO_STEPS
        aa_to_R(arg, step);
        float cur[9];
        for (int i = 0; i < 9; ++i) { cur[i] = R0[i]; rots[0][i] = R0[i]; }
        for (int k = 1; k < N_FRAMES; ++k) {
            float nxt[9];
            mat3mul(cur, step, nxt);               // rot = rot @ rot_step (sequential)
            for (int i = 0; i < 9; ++i) { cur[i] = nxt[i]; rots[k][i] = nxt[i]; }
        }
    }
    __syncthreads();

    float e = expv[0];
    float t0 = transl[0], t1 = transl[1], t2 = transl[2];   // trans_start
    float u0 = transl[3], u1 = transl[4], u2 = transl[5];   // translation term p=1

    for (int item = tid; item < N_FRAMES * N_VERTS; item += blockDim.x) {
        int k = item / N_VERTS, v = item - k * N_VERTS;
        float te = (float)((double)k / 3.0) * e;            // f32(linspace ti) * exp
        float vx = verts_in[v*3+0], vy = verts_in[v*3+1], vz = verts_in[v*3+2];
        const float* R = rots[k];
        float dx_ = (R[0] * vx + R[1] * vy) + R[2] * vz;
        float dy_ = (R[3] * vx + R[4] * vy) + R[5] * vz;
        float dz_ = (R[6] * vx + R[7] * vy) + R[8] * vz;
        float x = (dx_ + t0) + te * u0;
        float y = (dy_ + t1) + te * u1;
        float z = (dz_ + t2) + te * u2;
        z = z - 2.0f;                                       // v_cam = verts - [0,0,CAM_DIST]
        sv[k][v*3+0] = x; sv[k][v*3+1] = y; sv[k][v*3+2] = z;
    }
    __syncthreads();

    const float FOCAL = (float)(1.0 / tan(1.57 / 4.0));

    // One wave per frame; stable (order-preserving) compaction of valid faces.
    int w    = tid >> 6;                                    // frame
    int lane = tid & 63;
    unsigned long long lmask = (lane == 63) ? 0x7fffffffffffffffull
                                            : ((1ull << lane) - 1ull);
    int cnt = 0;
    for (int base = 0; base < N_FACES; base += 64) {        // 320 = 5*64 exact
        int f = base + lane;
        int i0 = faces[f*3+0], i1 = faces[f*3+1], i2 = faces[f*3+2];
        const float* A = &sv[w][i0*3];
        const float* B = &sv[w][i1*3];
        const float* C = &sv[w][i2*3];
        float ux = B[0] - A[0], uy = B[1] - A[1];
        float wx = C[0] - A[0], wy = C[1] - A[1];
        float nz = ux * wy - uy * wx;                       // sign of face-normal z
        float da = -A[2] + 1e-10f, db = -B[2] + 1e-10f, dc = -C[2] + 1e-10f;
        float ax = (FOCAL * A[0]) / da, ay = (FOCAL * A[1]) / da;
        float bx = (FOCAL * B[0]) / db, by = (FOCAL * B[1]) / db;
        float cx = (FOCAL * C[0]) / dc, cy = (FOCAL * C[1]) / dc;
        float e0x = bx - ax, e0y = by - ay;                 // a->b
        float e1x = cx - ax, e1y = cy - ay;                 // a->c
        float e12x = cx - bx, e12y = cy - by;               // b->c
        float den = e0x * e1y - e0y * e1x;
        bool dok = fabsf(den) > 1e-10f;
        bool valid = dok && (nz > 0.0f);
        unsigned long long m = __ballot(valid);
        if (valid) {
            float invden = 1.0f / den;
            float L2_0 = (e0x * e0x + e0y * e0y) + 1e-12f;
            float L2_1 = (e12x * e12x + e12y * e12y) + 1e-12f;
            float L2_2 = (e1x * e1x + e1y * e1y) + 1e-12f;  // |(-e1)|^2 == |e1|^2 exactly
            int pos = cnt + __popcll(m & lmask);
            float4* fd = (float4*)(faceData + (w * N_FACES + pos) * FD_STRIDE);
            fd[0] = make_float4(ax, ay, e0x, e0y);
            fd[1] = make_float4(e1x, e1y, invden, (float)f);
            fd[2] = make_float4(A[2], B[2], C[2], 1.0f / L2_0);
            fd[3] = make_float4(bx, by, e12x, e12y);
            fd[4] = make_float4(cx, cy, 1.0f / L2_1, 1.0f / L2_2);
        }
        cnt += __popcll(m);
    }
    if (lane == 0) faceCount[w] = cnt;
}

// ---------- kernel 2: per-pixel rasterization + texture sample ----------
// 8 lanes per pixel, lane `c` handles compacted faces c, c+8, ...; butterfly combine.

__global__ void __launch_bounds__(256)
raster_kernel(const int*   __restrict__ faceCount,
              const float* __restrict__ faceData,
              const float* __restrict__ ffeat,    // (320,3,2)
              const float* __restrict__ tex,      // (3,256,256)
              float* __restrict__ out,            // (4,4,128,128)
              float* __restrict__ maskbuf)        // (4,128,128)
{
    int frame = blockIdx.x >> 9;                   // 2048 blocks: 512 per frame
    int blk   = blockIdx.x & 511;
    int tid   = threadIdx.x;
    int chunk = tid & 7;
    int pix   = blk * 32 + (tid >> 3);             // 32 pixels per block
    int i = pix >> 7, j = pix & 127;

    int nv = faceCount[frame];                     // wave-uniform

    __shared__ float4 fd4[N_FACES * 5];
    const float4* g = (const float4*)(faceData + frame * N_FACES * FD_STRIDE);
    for (int idx = tid; idx < nv * 5; idx += 256)
        fd4[idx] = g[idx];
    __syncthreads();

    float px = (float)(-1.0 + 2.0 * (double)j / 127.0);   // xs = linspace(-1,1,128)
    float py = (float)( 1.0 - 2.0 * (double)i / 127.0);   // ys = linspace(1,-1,128)

    float best = -1e10f;
    int bestf = 0;                                 // original face index
    float bw0 = 0.0f, bw1 = 0.0f, bw2 = 0.0f;
    float P = 1.0f;

    for (int f = chunk; f < nv; f += CHUNKS) {
        const float4* d = &fd4[f * 5];
        float4 q0 = d[0], q1 = d[1], q2 = d[2], q3 = d[3], q4 = d[4];

        float dx = px - q0.x, dy = py - q0.y;
        float w1 = (dx * q1.y - dy * q1.x) * q1.z;         // (dx*e1y - dy*e1x)*invden
        float w2 = (q0.z * dy - q0.w * dx) * q1.z;         // (e0x*dy - e0y*dx)*invden
        float w0 = (1.0f - w1) - w2;
        bool inside = (w0 >= 0.0f) & (w1 >= 0.0f) & (w2 >= 0.0f);
        float zi = (w0 * q2.x + w1 * q2.y) + w2 * q2.z;
        float score = inside ? zi : -1e10f;
        if (score > best) {
            best = score; bestf = (int)q1.w; bw0 = w0; bw1 = w1; bw2 = w2;
        }

        // edge 0: a->b  (rx,ry = dx,dy)
        float t0 = fminf(fmaxf((dx * q0.z + dy * q0.w) * q2.w, 0.0f), 1.0f);
        float x0 = dx - t0 * q0.z, y0 = dy - t0 * q0.w;
        float dd = x0 * x0 + y0 * y0;
        // edge 1: b->c
        float rx1 = px - q3.x, ry1 = py - q3.y;
        float t1 = fminf(fmaxf((rx1 * q3.z + ry1 * q3.w) * q4.z, 0.0f), 1.0f);
        float x1 = rx1 - t1 * q3.z, y1 = ry1 - t1 * q3.w;
        dd = fminf(dd, x1 * x1 + y1 * y1);
        // edge 2: c->a  (edge vector = -e1, exact fp negation)
        float ex2 = -q1.x, ey2 = -q1.y;
        float rx2 = px - q4.x, ry2 = py - q4.y;
        float t2 = fminf(fmaxf((rx2 * ex2 + ry2 * ey2) * q4.w, 0.0f), 1.0f);
        float x2 = rx2 - t2 * ex2, y2 = ry2 - t2 * ey2;
        dd = fminf(dd, x2 * x2 + y2 * y2);

        float d2 = inside ? 0.0f : dd;
        float prob = __expf(-7000.0f * d2);
        P *= (1.0f - prob);
    }

    // butterfly combine across the 8 chunk lanes of this pixel
    for (int m = 1; m <= 4; m <<= 1) {
        float oS = __shfl_xor(best, m);
        int   oF = __shfl_xor(bestf, m);
        float o0 = __shfl_xor(bw0, m);
        float o1 = __shfl_xor(bw1, m);
        float o2 = __shfl_xor(bw2, m);
        bool take = (oS > best) || ((oS == best) && (oF < bestf));  // first-max
        if (take) { best = oS; bestf = oF; bw0 = o0; bw1 = o1; bw2 = o2; }
        P *= __shfl_xor(P, m);
    }

    if (chunk == 0) {
        bool hit = best != -1e10f;
        float uv0 = 0.0f, uv1 = 0.0f;
        if (hit) {
            const float* fp = ffeat + bestf * 6;
            uv0 = (fp[0] * bw0 + fp[2] * bw1) + fp[4] * bw2;
            uv1 = (fp[1] * bw0 + fp[3] * bw1) + fp[5] * bw2;
        }
        float u = fminf(fmaxf(uv0, 0.0f), 1.0f) * 255.0f;
        float v = (1.0f - fminf(fmaxf(uv1, 0.0f), 1.0f)) * 255.0f;
        float x0f = floorf(u), y0f = floorf(v);
        float fx = u - x0f, fy = v - y0f;
        int x0i = min(max((int)x0f, 0), 255);
        int x1i = min(x0i + 1, 255);
        int y0i = min(max((int)y0f, 0), 255);
        int y1i = min(y0i + 1, 255);

        for (int c = 0; c < 3; ++c) {
            const float* tc = tex + c * 65536;
            float t00 = tc[y0i * 256 + x0i];
            float t01 = tc[y0i * 256 + x1i];
            float t10 = tc[y1i * 256 + x0i];
            float t11 = tc[y1i * 256 + x1i];
            float val = (t00 * (1.0f - fx)) * (1.0f - fy);
            val = val + (t01 * fx) * (1.0f - fy);
            val = val + (t10 * (1.0f - fx)) * fy;
            val = val + (t11 * fx) * fy;
            out[((frame * 4 + c) * IMG_H + i) * IMG_W + j] = val;
        }
        maskbuf[(frame * IMG_H + i) * IMG_W + j] = 1.0f - P;
    }
}

// ---------- kernel 3: 5x5 erode (window min over valid region) ----------

__global__ void __launch_bounds__(256)
erode_kernel(const float* __restrict__ maskbuf, float* __restrict__ out)
{
    int frame = blockIdx.x >> 6;
    int pix = (blockIdx.x & 63) * 256 + threadIdx.x;
    int i = pix >> 7, j = pix & 127;
    float m = 1e30f;
    for (int di = -2; di <= 2; ++di) {
        int ii = i + di;
        if (ii < 0 || ii >= IMG_H) continue;
        for (int dj = -2; dj <= 2; ++dj) {
            int jj = j + dj;
            if (jj < 0 || jj >= IMG_W) continue;
            m = fminf(m, maskbuf[(frame * IMG_H + ii) * IMG_W + jj]);
        }
    }
    out[((frame * 4 + 3) * IMG_H + i) * IMG_W + j] = m;
}

// ---------- launcher ----------

extern "C" void kernel_launch(void* const* d_in, const int* in_sizes, int n_in,
                              void* d_out, int out_size, void* d_ws, size_t ws_size,
                              hipStream_t stream) {
    const float* vertices      = (const float*)d_in[0];
    const float* translation   = (const float*)d_in[1];
    const float* quaternion    = (const float*)d_in[2];
    const float* expv          = (const float*)d_in[3];
    const float* face_features = (const float*)d_in[4];
    const float* texture_maps  = (const float*)d_in[5];
    const int*   faces         = (const int*)d_in[6];
    float* out = (float*)d_out;

    int*   faceCount = (int*)d_ws;                            // 4 ints
    float* faceData  = (float*)d_ws + 4;                      // 4*320*20 floats
    float* maskbuf   = faceData + N_FRAMES * N_FACES * FD_STRIDE;

    setup_kernel<<<1, 256, 0, stream>>>(vertices, translation, quaternion, expv,
                                        faces, faceCount, faceData);
    raster_kernel<<<N_FRAMES * 512, 256, 0, stream>>>(faceCount, faceData,
                                                      face_features, texture_maps,
                                                      out, maskbuf);
    erode_kernel<<<N_FRAMES * 64, 256, 0, stream>>>(maskbuf, out);
}

// Round 4
// 91.668 us; speedup vs baseline: 1.9277x; 1.0475x over previous
//
#include <hip/hip_runtime.h>
#include <math.h>

#define N_FRAMES 4
#define N_FACES  320
#define N_VERTS  162
#define IMG_H    128
#define IMG_W    128
#define FD_STRIDE 24      // 6 float4s per compacted face
#define NWAVES   8        // waves per block = face-split factor

// Compacted per-face record (6 float4s):
//  q0: ax, ay, e0x, e0y            (a vertex, edge a->b)
//  q1: e1x, e1y, invden, origidx   (edge a->c, 1/denom, original face index)
//  q2: z0, z1, z2, invL2_0
//  q3: bx, by, e12x, e12y          (b vertex, edge b->c)
//  q4: cx, cy, invL2_1, invL2_2    (edge c->a = -e1 exactly)
//  q5: xmin, ymin, xmax, ymax      (projected bbox, for the exact cull)

// ---------- small math helpers (fp32, op-order matched to the JAX reference) ----------

__device__ __forceinline__ void q_to_aa(const float* q, float* aa) {
    float q1 = q[1], q2 = q[2], q3 = q[3];
    float sin_sq = (q1 * q1 + q2 * q2) + q3 * q3;
    float sin_t = sqrtf(sin_sq + 1e-20f);
    float cos_t = q[0];
    float two_theta = (cos_t < 0.0f) ? (2.0f * atan2f(-sin_t, -cos_t))
                                     : (2.0f * atan2f(sin_t, cos_t));
    float k = (sin_sq > 1e-12f) ? (two_theta / sin_t) : 2.0f;
    aa[0] = q1 * k; aa[1] = q2 * k; aa[2] = q3 * k;
}

__device__ __forceinline__ void aa_to_R(const float* aa, float* R) {
    float th = sqrtf(((aa[0] * aa[0] + aa[1] * aa[1]) + aa[2] * aa[2]) + 1e-12f);
    float kx = aa[0] / th, ky = aa[1] / th, kz = aa[2] / th;
    float K[9] = { 0.0f, -kz,  ky,
                   kz,  0.0f, -kx,
                  -ky,   kx, 0.0f };
    float s = sinf(th), c = cosf(th);
    float KK[9];
    for (int i = 0; i < 3; ++i)
        for (int j = 0; j < 3; ++j)
            KK[i*3+j] = (K[i*3+0] * K[0*3+j] + K[i*3+1] * K[1*3+j]) + K[i*3+2] * K[2*3+j];
    float omc = 1.0f - c;
    for (int i = 0; i < 9; ++i) {
        float eye = (i == 0 || i == 4 || i == 8) ? 1.0f : 0.0f;
        R[i] = (eye + s * K[i]) + omc * KK[i];
    }
}

__device__ __forceinline__ void mat3mul(const float* A, const float* B, float* C) {
    for (int i = 0; i < 3; ++i)
        for (int j = 0; j < 3; ++j)
            C[i*3+j] = (A[i*3+0] * B[0*3+j] + A[i*3+1] * B[1*3+j]) + A[i*3+2] * B[2*3+j];
}

// ---------- kernel 1: rotation chain, vertex transform, face setup + compaction ----------

__global__ void __launch_bounds__(256)
setup_kernel(const float* __restrict__ verts_in,   // 162*3
             const float* __restrict__ transl,     // 6 floats
             const float* __restrict__ quat,       // 8 floats
             const float* __restrict__ expv,       // 1 float
             const int*   __restrict__ faces,      // 320*3
             int*   __restrict__ faceCount,        // 4 ints
             float* __restrict__ faceData)         // 4*320*FD_STRIDE
{
    __shared__ float rots[N_FRAMES][9];
    __shared__ float sv[N_FRAMES][N_VERTS * 3];    // camera-space verts
    int tid = threadIdx.x;

    if (tid == 0) {
        float aa0[3], aa1[3], R0[9], step[9];
        q_to_aa(quat, aa0);
        aa_to_R(aa0, R0);
        q_to_aa(quat + 4, aa1);                    // angles (ROT_DIVIDE = 1)
        float e = expv[0];
        float arg[3];
        for (int i = 0; i < 3; ++i) arg[i] = (e * aa1[i]) / 4.0f;   // exp*angles/FMO_STEPS
        aa_to_R(arg, step);
        float cur[9];
        for (int i = 0; i < 9; ++i) { cur[i] = R0[i]; rots[0][i] = R0[i]; }
        for (int k = 1; k < N_FRAMES; ++k) {
            float nxt[9];
            mat3mul(cur, step, nxt);               // rot = rot @ rot_step (sequential)
            for (int i = 0; i < 9; ++i) { cur[i] = nxt[i]; rots[k][i] = nxt[i]; }
        }
    }
    __syncthreads();

    float e = expv[0];
    float t0 = transl[0], t1 = transl[1], t2 = transl[2];   // trans_start
    float u0 = transl[3], u1 = transl[4], u2 = transl[5];   // translation term p=1

    for (int item = tid; item < N_FRAMES * N_VERTS; item += blockDim.x) {
        int k = item / N_VERTS, v = item - k * N_VERTS;
        float te = (float)((double)k / 3.0) * e;            // f32(linspace ti) * exp
        float vx = verts_in[v*3+0], vy = verts_in[v*3+1], vz = verts_in[v*3+2];
        const float* R = rots[k];
        float dx_ = (R[0] * vx + R[1] * vy) + R[2] * vz;
        float dy_ = (R[3] * vx + R[4] * vy) + R[5] * vz;
        float dz_ = (R[6] * vx + R[7] * vy) + R[8] * vz;
        float x = (dx_ + t0) + te * u0;
        float y = (dy_ + t1) + te * u1;
        float z = (dz_ + t2) + te * u2;
        z = z - 2.0f;                                       // v_cam = verts - [0,0,CAM_DIST]
        sv[k][v*3+0] = x; sv[k][v*3+1] = y; sv[k][v*3+2] = z;
    }
    __syncthreads();

    const float FOCAL = (float)(1.0 / tan(1.57 / 4.0));

    // One wave per frame; stable (order-preserving) compaction of valid faces.
    int w    = tid >> 6;                                    // frame
    int lane = tid & 63;
    unsigned long long lmask = (lane == 63) ? 0x7fffffffffffffffull
                                            : ((1ull << lane) - 1ull);
    int cnt = 0;
    for (int base = 0; base < N_FACES; base += 64) {        // 320 = 5*64 exact
        int f = base + lane;
        int i0 = faces[f*3+0], i1 = faces[f*3+1], i2 = faces[f*3+2];
        const float* A = &sv[w][i0*3];
        const float* B = &sv[w][i1*3];
        const float* C = &sv[w][i2*3];
        float ux = B[0] - A[0], uy = B[1] - A[1];
        float wx = C[0] - A[0], wy = C[1] - A[1];
        float nz = ux * wy - uy * wx;                       // sign of face-normal z
        float da = -A[2] + 1e-10f, db = -B[2] + 1e-10f, dc = -C[2] + 1e-10f;
        float ax = (FOCAL * A[0]) / da, ay = (FOCAL * A[1]) / da;
        float bx = (FOCAL * B[0]) / db, by = (FOCAL * B[1]) / db;
        float cx = (FOCAL * C[0]) / dc, cy = (FOCAL * C[1]) / dc;
        float e0x = bx - ax, e0y = by - ay;                 // a->b
        float e1x = cx - ax, e1y = cy - ay;                 // a->c
        float e12x = cx - bx, e12y = cy - by;               // b->c
        float den = e0x * e1y - e0y * e1x;
        bool dok = fabsf(den) > 1e-10f;
        bool valid = dok && (nz > 0.0f);
        unsigned long long m = __ballot(valid);
        if (valid) {
            float invden = 1.0f / den;
            float L2_0 = (e0x * e0x + e0y * e0y) + 1e-12f;
            float L2_1 = (e12x * e12x + e12y * e12y) + 1e-12f;
            float L2_2 = (e1x * e1x + e1y * e1y) + 1e-12f;  // |(-e1)|^2 == |e1|^2 exactly
            int pos = cnt + __popcll(m & lmask);
            float4* fd = (float4*)(faceData + (w * N_FACES + pos) * FD_STRIDE);
            fd[0] = make_float4(ax, ay, e0x, e0y);
            fd[1] = make_float4(e1x, e1y, invden, (float)f);
            fd[2] = make_float4(A[2], B[2], C[2], 1.0f / L2_0);
            fd[3] = make_float4(bx, by, e12x, e12y);
            fd[4] = make_float4(cx, cy, 1.0f / L2_1, 1.0f / L2_2);
            fd[5] = make_float4(fminf(fminf(ax, bx), cx), fminf(fminf(ay, by), cy),
                                fmaxf(fmaxf(ax, bx), cx), fmaxf(fmaxf(ay, by), cy));
        }
        cnt += __popcll(m);
    }
    if (lane == 0) faceCount[w] = cnt;
}

// ---------- kernel 2: per-pixel rasterization + texture sample ----------
// Block = 512 threads = 8 waves, all covering one 16x4 pixel tile (1 px/lane).
// Wave w processes compacted faces w, w+8, ... with wave-uniform (scalar) loads.
// Exact bbox cull: bbox_d^2 > 0.003 => prob < 7.6e-10 => (1-prob)==1.0f exactly
// and the face cannot be inside -> skipping is bit-exact.

__global__ void __launch_bounds__(512)
raster_kernel(const int*   __restrict__ faceCount,
              const float* __restrict__ faceData,
              const float* __restrict__ ffeat,    // (320,3,2)
              const float* __restrict__ tex,      // (3,256,256)
              float* __restrict__ out,            // (4,4,128,128)
              float* __restrict__ maskbuf)        // (4,128,128)
{
    int frame = blockIdx.x >> 8;                   // 1024 blocks: 256 tiles/frame
    int blk   = blockIdx.x & 255;
    int tid   = threadIdx.x;
    int lane  = tid & 63;
    int wv    = __builtin_amdgcn_readfirstlane(tid >> 6);   // wave id, uniform
    int tile_x = blk & 7, tile_y = blk >> 3;
    int j = tile_x * 16 + (lane & 15);
    int i = tile_y * 4 + (lane >> 4);

    int nv = faceCount[frame];

    float px = (float)(-1.0 + 2.0 * (double)j / 127.0);   // xs = linspace(-1,1,128)
    float py = (float)( 1.0 - 2.0 * (double)i / 127.0);   // ys = linspace(1,-1,128)

    float best = -1e10f;
    int bestf = 0;                                 // original face index
    float bw0 = 0.0f, bw1 = 0.0f, bw2 = 0.0f;
    float P = 1.0f;

    const float* g = faceData + frame * N_FACES * FD_STRIDE;

    for (int f = wv; f < nv; f += NWAVES) {
        const float* d = g + f * FD_STRIDE;        // wave-uniform -> s_load
        float xmin = d[20], ymin = d[21], xmax = d[22], ymax = d[23];
        float cdx = fmaxf(fmaxf(xmin - px, px - xmax), 0.0f);
        float cdy = fmaxf(fmaxf(ymin - py, py - ymax), 0.0f);
        bool near = (cdx * cdx + cdy * cdy) <= 0.003f;
        if (!__any(near)) continue;                // exact skip (see header comment)

        float ax = d[0], ay = d[1], e0x = d[2], e0y = d[3];
        float e1x = d[4], e1y = d[5], invden = d[6], fidx = d[7];
        float z0 = d[8], z1 = d[9], z2 = d[10], invL2_0 = d[11];
        float bx = d[12], by = d[13], e12x = d[14], e12y = d[15];
        float cx = d[16], cy = d[17], invL2_1 = d[18], invL2_2 = d[19];

        float dx = px - ax, dy = py - ay;
        float w1 = (dx * e1y - dy * e1x) * invden;
        float w2 = (e0x * dy - e0y * dx) * invden;
        float w0 = (1.0f - w1) - w2;
        bool inside = (w0 >= 0.0f) & (w1 >= 0.0f) & (w2 >= 0.0f);
        float zi = (w0 * z0 + w1 * z1) + w2 * z2;
        float score = inside ? zi : -1e10f;
        if (score > best) {
            best = score; bestf = (int)fidx; bw0 = w0; bw1 = w1; bw2 = w2;
        }

        // edge 0: a->b
        float t0 = fminf(fmaxf((dx * e0x + dy * e0y) * invL2_0, 0.0f), 1.0f);
        float x0 = dx - t0 * e0x, y0 = dy - t0 * e0y;
        float dd = x0 * x0 + y0 * y0;
        // edge 1: b->c
        float rx1 = px - bx, ry1 = py - by;
        float t1 = fminf(fmaxf((rx1 * e12x + ry1 * e12y) * invL2_1, 0.0f), 1.0f);
        float x1 = rx1 - t1 * e12x, y1 = ry1 - t1 * e12y;
        dd = fminf(dd, x1 * x1 + y1 * y1);
        // edge 2: c->a (edge vector = -e1, exact fp negation)
        float ex2 = -e1x, ey2 = -e1y;
        float rx2 = px - cx, ry2 = py - cy;
        float t2 = fminf(fmaxf((rx2 * ex2 + ry2 * ey2) * invL2_2, 0.0f), 1.0f);
        float x2 = rx2 - t2 * ex2, y2 = ry2 - t2 * ey2;
        dd = fminf(dd, x2 * x2 + y2 * y2);

        float d2 = inside ? 0.0f : dd;
        float prob = __expf(-7000.0f * d2);
        P *= (1.0f - prob);
    }

    // cross-wave reduction through LDS (once per block)
    __shared__ float red[512 * 6];
    float* my = &red[tid * 6];
    my[0] = best; my[1] = __int_as_float(bestf);
    my[2] = bw0;  my[3] = bw1; my[4] = bw2; my[5] = P;
    __syncthreads();

    if (tid < 64) {
        float bb = red[tid * 6 + 0];
        int   bf = __float_as_int(red[tid * 6 + 1]);
        float r0 = red[tid * 6 + 2], r1 = red[tid * 6 + 3], r2 = red[tid * 6 + 4];
        float Pt = red[tid * 6 + 5];
        for (int w = 1; w < NWAVES; ++w) {
            const float* e = &red[(w * 64 + tid) * 6];
            float s = e[0]; int ff = __float_as_int(e[1]);
            if ((s > bb) || ((s == bb) && (ff < bf))) {
                bb = s; bf = ff; r0 = e[2]; r1 = e[3]; r2 = e[4];
            }
            Pt *= e[5];
        }

        bool hit = bb != -1e10f;
        float uv0 = 0.0f, uv1 = 0.0f;
        if (hit) {
            const float* fp = ffeat + bf * 6;
            uv0 = (fp[0] * r0 + fp[2] * r1) + fp[4] * r2;
            uv1 = (fp[1] * r0 + fp[3] * r1) + fp[5] * r2;
        }
        float u = fminf(fmaxf(uv0, 0.0f), 1.0f) * 255.0f;
        float v = (1.0f - fminf(fmaxf(uv1, 0.0f), 1.0f)) * 255.0f;
        float x0f = floorf(u), y0f = floorf(v);
        float fx = u - x0f, fy = v - y0f;
        int x0i = min(max((int)x0f, 0), 255);
        int x1i = min(x0i + 1, 255);
        int y0i = min(max((int)y0f, 0), 255);
        int y1i = min(y0i + 1, 255);

        for (int c = 0; c < 3; ++c) {
            const float* tc = tex + c * 65536;
            float t00 = tc[y0i * 256 + x0i];
            float t01 = tc[y0i * 256 + x1i];
            float t10 = tc[y1i * 256 + x0i];
            float t11 = tc[y1i * 256 + x1i];
            float val = (t00 * (1.0f - fx)) * (1.0f - fy);
            val = val + (t01 * fx) * (1.0f - fy);
            val = val + (t10 * (1.0f - fx)) * fy;
            val = val + (t11 * fx) * fy;
            out[((frame * 4 + c) * IMG_H + i) * IMG_W + j] = val;
        }
        maskbuf[(frame * IMG_H + i) * IMG_W + j] = 1.0f - Pt;
    }
}

// ---------- kernel 3: 5x5 erode (window min over valid region) ----------

__global__ void __launch_bounds__(256)
erode_kernel(const float* __restrict__ maskbuf, float* __restrict__ out)
{
    int frame = blockIdx.x >> 6;
    int pix = (blockIdx.x & 63) * 256 + threadIdx.x;
    int i = pix >> 7, j = pix & 127;
    float m = 1e30f;
    for (int di = -2; di <= 2; ++di) {
        int ii = i + di;
        if (ii < 0 || ii >= IMG_H) continue;
        for (int dj = -2; dj <= 2; ++dj) {
            int jj = j + dj;
            if (jj < 0 || jj >= IMG_W) continue;
            m = fminf(m, maskbuf[(frame * IMG_H + ii) * IMG_W + jj]);
        }
    }
    out[((frame * 4 + 3) * IMG_H + i) * IMG_W + j] = m;
}

// ---------- launcher ----------

extern "C" void kernel_launch(void* const* d_in, const int* in_sizes, int n_in,
                              void* d_out, int out_size, void* d_ws, size_t ws_size,
                              hipStream_t stream) {
    const float* vertices      = (const float*)d_in[0];
    const float* translation   = (const float*)d_in[1];
    const float* quaternion    = (const float*)d_in[2];
    const float* expv          = (const float*)d_in[3];
    const float* face_features = (const float*)d_in[4];
    const float* texture_maps  = (const float*)d_in[5];
    const int*   faces         = (const int*)d_in[6];
    float* out = (float*)d_out;

    int*   faceCount = (int*)d_ws;                            // 4 ints
    float* faceData  = (float*)d_ws + 4;                      // 4*320*24 floats
    float* maskbuf   = faceData + N_FRAMES * N_FACES * FD_STRIDE;

    setup_kernel<<<1, 256, 0, stream>>>(vertices, translation, quaternion, expv,
                                        faces, faceCount, faceData);
    raster_kernel<<<N_FRAMES * 256, 512, 0, stream>>>(faceCount, faceData,
                                                      face_features, texture_maps,
                                                      out, maskbuf);
    erode_kernel<<<N_FRAMES * 64, 256, 0, stream>>>(maskbuf, out);
}

// Round 5
// 90.150 us; speedup vs baseline: 1.9602x; 1.0168x over previous
//
#include <hip/hip_runtime.h>
#include <math.h>

#define N_FRAMES 4
#define N_FACES  320
#define N_VERTS  162
#define IMG_H    128
#define IMG_W    128
#define NWAVES   8
#define FPW      40            // faces per wave (320/8), fits in one ballot round
#define REC_SZ   20            // floats per compacted face record

// LDS arena layout (bytes):
//   sv    @ 0      : 162*3 floats = 1944  (rounded to 1952)
//   bbox  @ 1952   : SoA [wave][4][FPW+8] floats = 8*4*48*4 = 6144
//   recs  @ 8096   : [wave][FPW][REC_SZ] floats = 8*40*20*4 = 25600
//   total 33696; reduction buffer (512*6*4 = 12288) aliases offset 0 after a barrier.
#define SV_OFF   0
#define BB_OFF   1952
#define BB_LD    48            // padded leading dim for bbox SoA
#define REC_OFF  8096
#define ARENA_SZ 33696

// Record (REC_SZ floats): ax,ay,e0x,e0y, e1x,e1y,invden,origidx,
//                         z0,z1,z2,invL2_0, bx,by,e12x,e12y, cx,cy,invL2_1,invL2_2

// ---------- small math helpers (fp32, op-order matched to the JAX reference) ----------

__device__ __forceinline__ void q_to_aa(const float* q, float* aa) {
    float q1 = q[1], q2 = q[2], q3 = q[3];
    float sin_sq = (q1 * q1 + q2 * q2) + q3 * q3;
    float sin_t = sqrtf(sin_sq + 1e-20f);
    float cos_t = q[0];
    float two_theta = (cos_t < 0.0f) ? (2.0f * atan2f(-sin_t, -cos_t))
                                     : (2.0f * atan2f(sin_t, cos_t));
    float k = (sin_sq > 1e-12f) ? (two_theta / sin_t) : 2.0f;
    aa[0] = q1 * k; aa[1] = q2 * k; aa[2] = q3 * k;
}

__device__ __forceinline__ void aa_to_R(const float* aa, float* R) {
    float th = sqrtf(((aa[0] * aa[0] + aa[1] * aa[1]) + aa[2] * aa[2]) + 1e-12f);
    float kx = aa[0] / th, ky = aa[1] / th, kz = aa[2] / th;
    float K[9] = { 0.0f, -kz,  ky,
                   kz,  0.0f, -kx,
                  -ky,   kx, 0.0f };
    float s = sinf(th), c = cosf(th);
    float KK[9];
    for (int i = 0; i < 3; ++i)
        for (int j = 0; j < 3; ++j)
            KK[i*3+j] = (K[i*3+0] * K[0*3+j] + K[i*3+1] * K[1*3+j]) + K[i*3+2] * K[2*3+j];
    float omc = 1.0f - c;
    for (int i = 0; i < 9; ++i) {
        float eye = (i == 0 || i == 4 || i == 8) ? 1.0f : 0.0f;
        R[i] = (eye + s * K[i]) + omc * KK[i];
    }
}

__device__ __forceinline__ void mat3mul(const float* A, const float* B, float* C) {
    for (int i = 0; i < 3; ++i)
        for (int j = 0; j < 3; ++j)
            C[i*3+j] = (A[i*3+0] * B[0*3+j] + A[i*3+1] * B[1*3+j]) + A[i*3+2] * B[2*3+j];
}

// ---------- fused kernel: per-block setup + rasterization + texture sample ----------
// Block = 512 threads = 8 waves, one 16x4 pixel tile (1 px/lane), one frame.
// Prologue rebuilds this frame's face table in LDS (fp order identical to the
// reference; compaction order is irrelevant: argmax tie-breaks on ORIGINAL face
// index, and the mask product is order-tolerant).
// Cull: rect-rect distance^2 > 0.0026 => prob rounds to exactly 1.0f for every
// pixel in the tile and the face cannot be inside -> skipping is bit-exact.

__global__ void __launch_bounds__(512)
render_kernel(const float* __restrict__ verts_in,   // 162*3
              const float* __restrict__ transl,     // 6 floats
              const float* __restrict__ quat,       // 8 floats
              const float* __restrict__ expv,       // 1 float
              const int*   __restrict__ faces,      // 320*3
              const float* __restrict__ ffeat,      // (320,3,2)
              const float* __restrict__ tex,        // (3,256,256)
              float* __restrict__ out,              // (4,4,128,128)
              float* __restrict__ maskbuf)          // (4,128,128)
{
    __shared__ __align__(16) char arena[ARENA_SZ];
    float* sv   = (float*)(arena + SV_OFF);
    float* bb   = (float*)(arena + BB_OFF);
    float* recs = (float*)(arena + REC_OFF);
    float* red  = (float*)arena;                    // aliased; used after barrier

    int frame = blockIdx.x >> 8;                    // 1024 blocks: 256 tiles/frame
    int blk   = blockIdx.x & 255;
    int tid   = threadIdx.x;
    int lane  = tid & 63;
    int wv    = __builtin_amdgcn_readfirstlane(tid >> 6);
    int tile_x = blk & 7, tile_y = blk >> 3;
    int j = tile_x * 16 + (lane & 15);
    int i = tile_y * 4 + (lane >> 4);

    // ---- prologue phase 1: rotation chain (redundant per thread; wave-uniform) ----
    float e = expv[0];
    float R[9];
    {
        float aa0[3], aa1[3], S[9];
        q_to_aa(quat, aa0);
        aa_to_R(aa0, R);
        q_to_aa(quat + 4, aa1);                     // angles (ROT_DIVIDE = 1)
        float arg[3];
        for (int t = 0; t < 3; ++t) arg[t] = (e * aa1[t]) / 4.0f;
        aa_to_R(arg, S);
        for (int t = 0; t < frame; ++t) {           // rot = rot @ rot_step, k times
            float nxt[9];
            mat3mul(R, S, nxt);
            for (int q = 0; q < 9; ++q) R[q] = nxt[q];
        }
    }

    // ---- prologue phase 2: camera-space vertices for THIS frame ----
    if (tid < N_VERTS) {
        float te = (float)((double)frame / 3.0) * e;
        float vx = verts_in[tid*3+0], vy = verts_in[tid*3+1], vz = verts_in[tid*3+2];
        float dx_ = (R[0] * vx + R[1] * vy) + R[2] * vz;
        float dy_ = (R[3] * vx + R[4] * vy) + R[5] * vz;
        float dz_ = (R[6] * vx + R[7] * vy) + R[8] * vz;
        float x = (dx_ + transl[0]) + te * transl[3];
        float y = (dy_ + transl[1]) + te * transl[4];
        float z = (dz_ + transl[2]) + te * transl[5];
        z = z - 2.0f;                               // v_cam = verts - [0,0,CAM_DIST]
        sv[tid*3+0] = x; sv[tid*3+1] = y; sv[tid*3+2] = z;
    }
    __syncthreads();

    // ---- prologue phase 3: per-wave face setup + ballot compaction ----
    const float FOCAL = (float)(1.0 / tan(1.57 / 4.0));
    int cnt;
    {
        bool valid = false;
        float ax=0, ay=0, bx=0, by=0, cx=0, cy=0, e0x=0, e0y=0, e1x=0, e1y=0;
        float e12x=0, e12y=0, z0=0, z1=0, z2=0, den=0;
        int f = wv * FPW + lane;
        if (lane < FPW) {
            int i0 = faces[f*3+0], i1 = faces[f*3+1], i2 = faces[f*3+2];
            const float* A = &sv[i0*3];
            const float* B = &sv[i1*3];
            const float* C = &sv[i2*3];
            float ux = B[0] - A[0], uy = B[1] - A[1];
            float wx = C[0] - A[0], wy = C[1] - A[1];
            float nz = ux * wy - uy * wx;           // sign of face-normal z
            float da = -A[2] + 1e-10f, db = -B[2] + 1e-10f, dc = -C[2] + 1e-10f;
            ax = (FOCAL * A[0]) / da; ay = (FOCAL * A[1]) / da;
            bx = (FOCAL * B[0]) / db; by = (FOCAL * B[1]) / db;
            cx = (FOCAL * C[0]) / dc; cy = (FOCAL * C[1]) / dc;
            e0x = bx - ax; e0y = by - ay;           // a->b
            e1x = cx - ax; e1y = cy - ay;           // a->c
            e12x = cx - bx; e12y = cy - by;         // b->c
            den = e0x * e1y - e0y * e1x;
            z0 = A[2]; z1 = B[2]; z2 = C[2];
            valid = (fabsf(den) > 1e-10f) && (nz > 0.0f);
        }
        unsigned long long m = __ballot(valid);
        cnt = __popcll(m);                          // wave-uniform
        if (valid) {
            unsigned long long lmask = (lane == 63) ? 0x7fffffffffffffffull
                                                    : ((1ull << lane) - 1ull);
            int pos = __popcll(m & lmask);
            float invden = 1.0f / den;
            float L2_0 = (e0x * e0x + e0y * e0y) + 1e-12f;
            float L2_1 = (e12x * e12x + e12y * e12y) + 1e-12f;
            float L2_2 = (e1x * e1x + e1y * e1y) + 1e-12f;   // |(-e1)|^2 == |e1|^2
            float4* r = (float4*)&recs[(wv * FPW + pos) * REC_SZ];
            r[0] = make_float4(ax, ay, e0x, e0y);
            r[1] = make_float4(e1x, e1y, invden, (float)f);
            r[2] = make_float4(z0, z1, z2, 1.0f / L2_0);
            r[3] = make_float4(bx, by, e12x, e12y);
            r[4] = make_float4(cx, cy, 1.0f / L2_1, 1.0f / L2_2);
            float* wbb = &bb[wv * 4 * BB_LD];
            wbb[0*BB_LD + pos] = fminf(fminf(ax, bx), cx);   // xmin
            wbb[1*BB_LD + pos] = fminf(fminf(ay, by), cy);   // ymin
            wbb[2*BB_LD + pos] = fmaxf(fmaxf(ax, bx), cx);   // xmax
            wbb[3*BB_LD + pos] = fmaxf(fmaxf(ay, by), cy);   // ymax
        }
    }
    // No barrier needed: each wave reads only its own compacted segment.

    // ---- per-pixel coordinates & wave tile rectangle ----
    float px = (float)(-1.0 + 2.0 * (double)j / 127.0);
    float py = (float)( 1.0 - 2.0 * (double)i / 127.0);
    float txmin = (float)(-1.0 + 2.0 * (double)(tile_x * 16) / 127.0);
    float txmax = (float)(-1.0 + 2.0 * (double)(tile_x * 16 + 15) / 127.0);
    float tymax = (float)( 1.0 - 2.0 * (double)(tile_y * 4) / 127.0);
    float tymin = (float)( 1.0 - 2.0 * (double)(tile_y * 4 + 3) / 127.0);

    // ---- cull pass: one vectorized bbox test per lane -> relevance bitmask ----
    unsigned long long fmask;
    {
        int l = (lane < FPW) ? lane : 0;
        const float* wbb = &bb[wv * 4 * BB_LD];
        float xmin = wbb[0*BB_LD + l], ymin = wbb[1*BB_LD + l];
        float xmax = wbb[2*BB_LD + l], ymax = wbb[3*BB_LD + l];
        float cdx = fmaxf(fmaxf(xmin - txmax, txmin - xmax), 0.0f);
        float cdy = fmaxf(fmaxf(ymin - tymax, tymin - ymax), 0.0f);
        bool near = ((cdx * cdx + cdy * cdy) <= 0.0026f) && (lane < cnt);
        fmask = __ballot(near);
    }

    // ---- main loop: only relevant faces ----
    float best = -1e10f;
    int bestf = 0;
    float bw0 = 0.0f, bw1 = 0.0f, bw2 = 0.0f;
    float P = 1.0f;

    while (fmask) {
        int fc = __ffsll((unsigned long long)fmask) - 1;   // wave-uniform
        fmask &= fmask - 1;
        const float* d = &recs[(wv * FPW + fc) * REC_SZ];  // uniform -> broadcast

        float ax = d[0], ay = d[1], e0x = d[2], e0y = d[3];
        float e1x = d[4], e1y = d[5], invden = d[6], fidx = d[7];
        float z0 = d[8], z1 = d[9], z2 = d[10], invL2_0 = d[11];
        float bx = d[12], by = d[13], e12x = d[14], e12y = d[15];
        float cx = d[16], cy = d[17], invL2_1 = d[18], invL2_2 = d[19];

        float dx = px - ax, dy = py - ay;
        float w1 = (dx * e1y - dy * e1x) * invden;
        float w2 = (e0x * dy - e0y * dx) * invden;
        float w0 = (1.0f - w1) - w2;
        bool inside = (w0 >= 0.0f) & (w1 >= 0.0f) & (w2 >= 0.0f);
        float zi = (w0 * z0 + w1 * z1) + w2 * z2;
        float score = inside ? zi : -1e10f;
        if (score > best) {
            best = score; bestf = (int)fidx; bw0 = w0; bw1 = w1; bw2 = w2;
        }

        // edge 0: a->b
        float t0 = fminf(fmaxf((dx * e0x + dy * e0y) * invL2_0, 0.0f), 1.0f);
        float x0 = dx - t0 * e0x, y0 = dy - t0 * e0y;
        float dd = x0 * x0 + y0 * y0;
        // edge 1: b->c
        float rx1 = px - bx, ry1 = py - by;
        float t1 = fminf(fmaxf((rx1 * e12x + ry1 * e12y) * invL2_1, 0.0f), 1.0f);
        float x1 = rx1 - t1 * e12x, y1 = ry1 - t1 * e12y;
        dd = fminf(dd, x1 * x1 + y1 * y1);
        // edge 2: c->a (edge vector = -e1, exact fp negation)
        float ex2 = -e1x, ey2 = -e1y;
        float rx2 = px - cx, ry2 = py - cy;
        float t2 = fminf(fmaxf((rx2 * ex2 + ry2 * ey2) * invL2_2, 0.0f), 1.0f);
        float x2 = rx2 - t2 * ex2, y2 = ry2 - t2 * ey2;
        dd = fminf(dd, x2 * x2 + y2 * y2);

        float d2 = inside ? 0.0f : dd;
        float prob = __expf(-7000.0f * d2);
        P *= (1.0f - prob);
    }

    // ---- cross-wave reduction (red aliases the arena: barrier both sides) ----
    __syncthreads();                               // all waves done with recs/bb
    float* my = &red[tid * 6];
    my[0] = best; my[1] = __int_as_float(bestf);
    my[2] = bw0;  my[3] = bw1; my[4] = bw2; my[5] = P;
    __syncthreads();

    if (tid < 64) {
        float bbst = red[tid * 6 + 0];
        int   bf   = __float_as_int(red[tid * 6 + 1]);
        float r0 = red[tid * 6 + 2], r1 = red[tid * 6 + 3], r2 = red[tid * 6 + 4];
        float Pt = red[tid * 6 + 5];
        for (int w = 1; w < NWAVES; ++w) {
            const float* s = &red[(w * 64 + tid) * 6];
            float sc = s[0]; int ff = __float_as_int(s[1]);
            if ((sc > bbst) || ((sc == bbst) && (ff < bf))) {
                bbst = sc; bf = ff; r0 = s[2]; r1 = s[3]; r2 = s[4];
            }
            Pt *= s[5];
        }

        bool hit = bbst != -1e10f;
        float uv0 = 0.0f, uv1 = 0.0f;
        if (hit) {
            const float* fp = ffeat + bf * 6;
            uv0 = (fp[0] * r0 + fp[2] * r1) + fp[4] * r2;
            uv1 = (fp[1] * r0 + fp[3] * r1) + fp[5] * r2;
        }
        float u = fminf(fmaxf(uv0, 0.0f), 1.0f) * 255.0f;
        float v = (1.0f - fminf(fmaxf(uv1, 0.0f), 1.0f)) * 255.0f;
        float x0f = floorf(u), y0f = floorf(v);
        float fx = u - x0f, fy = v - y0f;
        int x0i = min(max((int)x0f, 0), 255);
        int x1i = min(x0i + 1, 255);
        int y0i = min(max((int)y0f, 0), 255);
        int y1i = min(y0i + 1, 255);

        for (int c = 0; c < 3; ++c) {
            const float* tc = tex + c * 65536;
            float t00 = tc[y0i * 256 + x0i];
            float t01 = tc[y0i * 256 + x1i];
            float t10 = tc[y1i * 256 + x0i];
            float t11 = tc[y1i * 256 + x1i];
            float val = (t00 * (1.0f - fx)) * (1.0f - fy);
            val = val + (t01 * fx) * (1.0f - fy);
            val = val + (t10 * (1.0f - fx)) * fy;
            val = val + (t11 * fx) * fy;
            out[((frame * 4 + c) * IMG_H + i) * IMG_W + j] = val;
        }
        maskbuf[(frame * IMG_H + i) * IMG_W + j] = 1.0f - Pt;
    }
}

// ---------- kernel 2: 5x5 erode (window min over valid region) ----------

__global__ void __launch_bounds__(256)
erode_kernel(const float* __restrict__ maskbuf, float* __restrict__ out)
{
    int frame = blockIdx.x >> 6;
    int pix = (blockIdx.x & 63) * 256 + threadIdx.x;
    int i = pix >> 7, j = pix & 127;
    float m = 1e30f;
    for (int di = -2; di <= 2; ++di) {
        int ii = i + di;
        if (ii < 0 || ii >= IMG_H) continue;
        for (int dj = -2; dj <= 2; ++dj) {
            int jj = j + dj;
            if (jj < 0 || jj >= IMG_W) continue;
            m = fminf(m, maskbuf[(frame * IMG_H + ii) * IMG_W + jj]);
        }
    }
    out[((frame * 4 + 3) * IMG_H + i) * IMG_W + j] = m;
}

// ---------- launcher ----------

extern "C" void kernel_launch(void* const* d_in, const int* in_sizes, int n_in,
                              void* d_out, int out_size, void* d_ws, size_t ws_size,
                              hipStream_t stream) {
    const float* vertices      = (const float*)d_in[0];
    const float* translation   = (const float*)d_in[1];
    const float* quaternion    = (const float*)d_in[2];
    const float* expv          = (const float*)d_in[3];
    const float* face_features = (const float*)d_in[4];
    const float* texture_maps  = (const float*)d_in[5];
    const int*   faces         = (const int*)d_in[6];
    float* out = (float*)d_out;

    float* maskbuf = (float*)d_ws;                 // 4*128*128 floats

    render_kernel<<<N_FRAMES * 256, 512, 0, stream>>>(vertices, translation,
                                                      quaternion, expv, faces,
                                                      face_features, texture_maps,
                                                      out, maskbuf);
    erode_kernel<<<N_FRAMES * 64, 256, 0, stream>>>(maskbuf, out);
}